// Round 4
// baseline (1970.813 us; speedup 1.0000x reference)
//
#include <hip/hip_runtime.h>

#define NN  100000
#define SEQ 12

// d_ws float offsets (repacked weights)
#define OFF_UV   0        // [32][8]: k*8 + {u_i,u_f,u_g,u_o, v_i,v_f,v_g,v_o}
#define OFF_W0   256      // [32][4][32]  Whh0 rows grouped per unit k
#define OFF_W1   4352     // [32][4][64]  [Wih1 | Whh1] rows grouped per unit k
#define OFF_B1   12544    // [32][4]      bih1+bhh1
#define OFF_FC1  12672    // [16][32]     W_fc1 transposed
#define OFF_BFC1 13184    // [16]
#define OFF_FC2  13200    // [16]
#define OFF_BFC2 13216    // [1]

__device__ __forceinline__ float rcp_fast(float v) { return __builtin_amdgcn_rcpf(v); }
__device__ __forceinline__ float sigm(float v) { return rcp_fast(1.0f + __expf(-v)); }
__device__ __forceinline__ float tanh_fast(float v) {
    return fmaf(-2.0f, rcp_fast(1.0f + __expf(2.0f * v)), 1.0f);
}

// One-block repack: fold temporal_proj into layer-0 input projection, regroup
// all LSTM weights unit-major so the main kernel streams them with uniform
// (scalar) loads, pre-sum biases, transpose fc1.
__global__ void repack(const float* __restrict__ Wtp,  const float* __restrict__ btp,
                       const float* __restrict__ Wih0, const float* __restrict__ Whh0,
                       const float* __restrict__ bih0, const float* __restrict__ bhh0,
                       const float* __restrict__ Wih1, const float* __restrict__ Whh1,
                       const float* __restrict__ bih1, const float* __restrict__ bhh1,
                       const float* __restrict__ Wfc1, const float* __restrict__ bfc1,
                       const float* __restrict__ Wfc2, const float* __restrict__ bfc2,
                       float* __restrict__ ws)
{
    const int tid = threadIdx.x;  // 256 threads
    if (tid < 128) {
        int k = tid >> 2, g = tid & 3;
        int r = g * 32 + k;                 // PyTorch gate-major row (i,f,g,o)
        float u = 0.f, v = 0.f;
        for (int d = 0; d < 16; ++d) {
            u = fmaf(Wih0[r * 16 + d], Wtp[d], u);
            v = fmaf(Wih0[r * 16 + d], btp[d], v);
        }
        ws[OFF_UV + k * 8 + g]     = u;
        ws[OFF_UV + k * 8 + 4 + g] = v + bih0[r] + bhh0[r];
        ws[OFF_B1 + tid]           = bih1[r] + bhh1[r];   // [k*4+g]
    }
    for (int idx = tid; idx < 4096; idx += 256) {
        int k = idx >> 7, rem = idx & 127, g = rem >> 5, j = rem & 31;
        ws[OFF_W0 + idx] = Whh0[(g * 32 + k) * 32 + j];
    }
    for (int idx = tid; idx < 8192; idx += 256) {
        int k = idx >> 8, rem = idx & 255, g = rem >> 6, j = rem & 63;
        ws[OFF_W1 + idx] = (j < 32) ? Wih1[(g * 32 + k) * 32 + j]
                                    : Whh1[(g * 32 + k) * 32 + j - 32];
    }
    for (int idx = tid; idx < 512; idx += 256) {
        int m = idx >> 5, j = idx & 31;
        ws[OFF_FC1 + idx] = Wfc1[j * 16 + m];
    }
    if (tid < 16) { ws[OFF_BFC1 + tid] = bfc1[tid]; ws[OFF_FC2 + tid] = Wfc2[tid]; }
    if (tid == 0) ws[OFF_BFC2] = bfc2[0];
}

// 64 nodes per block (one per lane); the block's 4 waves split the 32 LSTM
// units: wave w owns units [8w, 8w+8) of BOTH layers. Weight addresses are
// wave-uniform (forced via readfirstlane) -> pure s_load broadcast, zero LDS
// for weights. Per-thread state ~100 floats fits the 128-VGPR budget
// (amdgpu_waves_per_eu(4,4) pins it) -> no scratch spills (R3: 160-float
// state at VGPR=104 spilled -> 29 MB HBM writes). Waves exchange h-slices
// via transposed LDS sH[unit][lane] (2-way bank alias = free); each
// write<->read pair is barrier-separated, so a single buffer is race-free.
__global__ __launch_bounds__(256) __attribute__((amdgpu_waves_per_eu(4, 4)))
void lstm_main(const float* __restrict__ x, const float* __restrict__ ws,
               float* __restrict__ out)
{
    __shared__ float sH0[32][64];
    __shared__ float sH1[32][64];

    const int tid  = threadIdx.x;
    const int lane = tid & 63;
    const int wv   = __builtin_amdgcn_readfirstlane(tid >> 6);  // wave id 0..3
    const int node = blockIdx.x * 64 + lane;
    const bool valid = node < NN;
    const int K0 = wv * 8;                   // owned units [K0, K0+8)

    float xv[SEQ];
    {
        const float4* xp = (const float4*)(x + (size_t)(valid ? node : 0) * 32 + 20);
        float4 a = xp[0], b = xp[1], c = xp[2];
        xv[0] = a.x; xv[1] = a.y; xv[2]  = a.z; xv[3]  = a.w;
        xv[4] = b.x; xv[5] = b.y; xv[6]  = b.z; xv[7]  = b.w;
        xv[8] = c.x; xv[9] = c.y; xv[10] = c.z; xv[11] = c.w;
    }

    float h0[32], h1[32], c0[8], c1[8], hn[8];
#pragma unroll
    for (int j = 0; j < 32; ++j) { h0[j] = 0.f; h1[j] = 0.f; }
#pragma unroll
    for (int k = 0; k < 8; ++k) { c0[k] = 0.f; c1[k] = 0.f; }

#pragma unroll 1
    for (int t = 0; t < SEQ; ++t) {
        const float xt = xv[t];

        // ---------------- layer 0: own 8 units ----------------
#pragma unroll
        for (int k = 0; k < 8; ++k) {
            const int K = K0 + k;
            const float* uv = ws + OFF_UV + K * 8;     // uniform -> s_load
            const float* wp = ws + OFF_W0 + K * 128;
            float ai = fmaf(xt, uv[0], uv[4]);
            float af = fmaf(xt, uv[1], uv[5]);
            float ag = fmaf(xt, uv[2], uv[6]);
            float ao = fmaf(xt, uv[3], uv[7]);
#pragma unroll
            for (int j = 0; j < 32; ++j) {
                const float hj = h0[j];
                ai = fmaf(wp[j],      hj, ai);
                af = fmaf(wp[32 + j], hj, af);
                ag = fmaf(wp[64 + j], hj, ag);
                ao = fmaf(wp[96 + j], hj, ao);
            }
            const float gi = sigm(ai), gf = sigm(af);
            const float gg = tanh_fast(ag), go = sigm(ao);
            const float cc = fmaf(gf, c0[k], gi * gg);
            c0[k] = cc;
            hn[k] = go * tanh_fast(cc);
        }
        // exchange: publish own slice, gather full h0_new
#pragma unroll
        for (int k = 0; k < 8; ++k) sH0[K0 + k][lane] = hn[k];
        __syncthreads();
#pragma unroll
        for (int j = 0; j < 32; ++j) h0[j] = sH0[j][lane];

        // ---------------- layer 1: own 8 units ----------------
#pragma unroll
        for (int k = 0; k < 8; ++k) {
            const int K = K0 + k;
            const float* wp = ws + OFF_W1 + K * 256;   // [g][64]: j<32 -> h0_new, j>=32 -> h1_old
            const float* bp = ws + OFF_B1 + K * 4;
            float ai = bp[0], af = bp[1], ag = bp[2], ao = bp[3];
#pragma unroll
            for (int j = 0; j < 32; ++j) {
                const float hj = h0[j];
                ai = fmaf(wp[j],       hj, ai);
                af = fmaf(wp[64 + j],  hj, af);
                ag = fmaf(wp[128 + j], hj, ag);
                ao = fmaf(wp[192 + j], hj, ao);
            }
#pragma unroll
            for (int j = 0; j < 32; ++j) {
                const float hj = h1[j];
                ai = fmaf(wp[32 + j],  hj, ai);
                af = fmaf(wp[96 + j],  hj, af);
                ag = fmaf(wp[160 + j], hj, ag);
                ao = fmaf(wp[224 + j], hj, ao);
            }
            const float gi = sigm(ai), gf = sigm(af);
            const float gg = tanh_fast(ag), go = sigm(ao);
            const float cc = fmaf(gf, c1[k], gi * gg);
            c1[k] = cc;
            hn[k] = go * tanh_fast(cc);
        }
#pragma unroll
        for (int k = 0; k < 8; ++k) sH1[K0 + k][lane] = hn[k];
        __syncthreads();
#pragma unroll
        for (int j = 0; j < 32; ++j) h1[j] = sH1[j][lane];
    }

    // ---------------- fc head: wave 0 only ----------------
    if (wv == 0 && valid) {
        float acc = ws[OFF_BFC2];
#pragma unroll
        for (int m = 0; m < 16; ++m) {
            const float* fp = ws + OFF_FC1 + m * 32;
            float y = ws[OFF_BFC1 + m];
#pragma unroll
            for (int j = 0; j < 32; ++j) y = fmaf(fp[j], h1[j], y);
            acc = fmaf(fmaxf(y, 0.f), ws[OFF_FC2 + m], acc);
        }
        out[node] = acc;
    }
}

extern "C" void kernel_launch(void* const* d_in, const int* in_sizes, int n_in,
                              void* d_out, int out_size, void* d_ws, size_t ws_size,
                              hipStream_t stream) {
    (void)in_sizes; (void)n_in; (void)out_size; (void)ws_size;
    const float* x    = (const float*)d_in[0];
    // d_in[1] edge_index and d_in[2..9] (GCN weights) are dead code in the reference
    const float* Wtp  = (const float*)d_in[10];
    const float* btp  = (const float*)d_in[11];
    const float* Wih0 = (const float*)d_in[12];
    const float* Whh0 = (const float*)d_in[13];
    const float* bih0 = (const float*)d_in[14];
    const float* bhh0 = (const float*)d_in[15];
    const float* Wih1 = (const float*)d_in[16];
    const float* Whh1 = (const float*)d_in[17];
    const float* bih1 = (const float*)d_in[18];
    const float* bhh1 = (const float*)d_in[19];
    const float* Wfc1 = (const float*)d_in[20];
    const float* bfc1 = (const float*)d_in[21];
    const float* Wfc2 = (const float*)d_in[22];
    const float* bfc2 = (const float*)d_in[23];
    float* ws  = (float*)d_ws;
    float* out = (float*)d_out;

    hipLaunchKernelGGL(repack, dim3(1), dim3(256), 0, stream,
                       Wtp, btp, Wih0, Whh0, bih0, bhh0,
                       Wih1, Whh1, bih1, bhh1, Wfc1, bfc1, Wfc2, bfc2, ws);
    hipLaunchKernelGGL(lstm_main, dim3((NN + 63) / 64), dim3(256), 0, stream,
                       x, ws, out);
}

// Round 5
// 1070.655 us; speedup vs baseline: 1.8408x; 1.8408x over previous
//
#include <hip/hip_runtime.h>

#define NN  100000
#define SEQ 12

// d_ws float offsets (repacked weights)
#define OFF_UV   0        // [32][8]: k*8 + {u_i,u_f,u_g,u_o, v_i,v_f,v_g,v_o}
#define OFF_W0   256      // [4][8][128]:  (wave, j4, u*16+g*4+jj)  layer-0 Whh
#define OFF_W1   4352     // [4][16][128]: (wave, j4, u*16+g*4+jj)  [Wih1|Whh1]
#define OFF_B1   12544    // [32][4]       bih1+bhh1
#define OFF_FC1  12672    // [16][32]      W_fc1 transposed
#define OFF_BFC1 13184    // [16]
#define OFF_FC2  13200    // [16]
#define OFF_BFC2 13216    // [1]

__device__ __forceinline__ float rcp_fast(float v) { return __builtin_amdgcn_rcpf(v); }
__device__ __forceinline__ float sigm(float v) { return rcp_fast(1.0f + __expf(-v)); }
__device__ __forceinline__ float tanh_fast(float v) {
    return fmaf(-2.0f, rcp_fast(1.0f + __expf(2.0f * v)), 1.0f);
}

// One-block repack: fold temporal_proj into layer-0 input projection; lay all
// LSTM weights out in the main kernel's exact scalar consumption order.
__global__ void repack(const float* __restrict__ Wtp,  const float* __restrict__ btp,
                       const float* __restrict__ Wih0, const float* __restrict__ Whh0,
                       const float* __restrict__ bih0, const float* __restrict__ bhh0,
                       const float* __restrict__ Wih1, const float* __restrict__ Whh1,
                       const float* __restrict__ bih1, const float* __restrict__ bhh1,
                       const float* __restrict__ Wfc1, const float* __restrict__ bfc1,
                       const float* __restrict__ Wfc2, const float* __restrict__ bfc2,
                       float* __restrict__ ws)
{
    const int tid = threadIdx.x;  // 256 threads
    if (tid < 128) {
        int k = tid >> 2, g = tid & 3;
        int r = g * 32 + k;                 // PyTorch gate-major row (i,f,g,o)
        float u = 0.f, v = 0.f;
        for (int d = 0; d < 16; ++d) {
            u = fmaf(Wih0[r * 16 + d], Wtp[d], u);
            v = fmaf(Wih0[r * 16 + d], btp[d], v);
        }
        ws[OFF_UV + k * 8 + g]     = u;
        ws[OFF_UV + k * 8 + 4 + g] = v + bih0[r] + bhh0[r];
        ws[OFF_B1 + tid]           = bih1[r] + bhh1[r];   // [k*4+g]
    }
    for (int idx = tid; idx < 4096; idx += 256) {
        int w = idx >> 10, rem = idx & 1023;
        int j4 = rem >> 7, rem2 = rem & 127;
        int u = rem2 >> 4, g = (rem2 >> 2) & 3, jj = rem2 & 3;
        int K = w * 8 + u, r = g * 32 + K;
        ws[OFF_W0 + idx] = Whh0[r * 32 + j4 * 4 + jj];
    }
    for (int idx = tid; idx < 8192; idx += 256) {
        int w = idx >> 11, rem = idx & 2047;
        int j4 = rem >> 7, rem2 = rem & 127;
        int u = rem2 >> 4, g = (rem2 >> 2) & 3, jj = rem2 & 3;
        int K = w * 8 + u, r = g * 32 + K;
        ws[OFF_W1 + idx] = (j4 < 8) ? Wih1[r * 32 + j4 * 4 + jj]
                                    : Whh1[r * 32 + (j4 - 8) * 4 + jj];
    }
    for (int idx = tid; idx < 512; idx += 256) {
        int m = idx >> 5, j = idx & 31;
        ws[OFF_FC1 + idx] = Wfc1[j * 16 + m];
    }
    if (tid < 16) { ws[OFF_BFC1 + tid] = bfc1[tid]; ws[OFF_FC2 + tid] = Wfc2[tid]; }
    if (tid == 0) ws[OFF_BFC2] = bfc2[0];
}

// 64 nodes/block (one per lane); wave w owns units [8w,8w+8) of both layers.
// Weights: wave-uniform -> s_load broadcast. Hidden state lives in LDS
// (double-buffered, odd stride 33 -> bank (lane+j)%32, conflict-free), read
// 4 values at a time feeding 128 FMAs. Per-thread regs ~70 (acc[8][4] +
// c0[8] + c1[8] + temps).
// LDS = 33792 B is deliberate: 4 blocks/CU -> 16 waves/CU -> 4 waves/EU ->
// the allocator's 128-VGPR budget (R1/R4 evidence: budget = 512/(LDS-implied
// waves/EU); waves_per_eu attrs are ignored). No spills at ~70 live regs.
__global__ __launch_bounds__(256)
void lstm_main(const float* __restrict__ x, const float* __restrict__ ws,
               float* __restrict__ out)
{
    __shared__ float sH0[2][64][33];
    __shared__ float sH1[2][64][33];

    const int tid  = threadIdx.x;
    const int lane = tid & 63;
    const int wv   = __builtin_amdgcn_readfirstlane(tid >> 6);  // wave id 0..3
    const int node = blockIdx.x * 64 + lane;
    const bool valid = node < NN;
    const int xnode = valid ? node : 0;
    const int K0   = wv * 8;                 // owned units [K0, K0+8)

    float c0[8], c1[8];
#pragma unroll
    for (int k = 0; k < 8; ++k) {
        c0[k] = 0.f; c1[k] = 0.f;
        sH0[0][lane][K0 + k] = 0.f;
        sH1[0][lane][K0 + k] = 0.f;
    }
    __syncthreads();

    const float* uvp = ws + OFF_UV + K0 * 8;   // uniform -> s_load
    const float* b1p = ws + OFF_B1 + K0 * 4;

    float xtn = x[(size_t)xnode * 32 + 20];    // software-pipelined x (no xv[t]!)

#pragma unroll 1
    for (int t = 0; t < SEQ; ++t) {
        const int p = t & 1, np = p ^ 1;
        const float xt = xtn;
        if (t + 1 < SEQ) xtn = x[(size_t)xnode * 32 + 21 + t];

        float acc[8][4];

        // ---------------- layer 0 ----------------
#pragma unroll
        for (int u = 0; u < 8; ++u) {
            acc[u][0] = fmaf(xt, uvp[u * 8 + 0], uvp[u * 8 + 4]);
            acc[u][1] = fmaf(xt, uvp[u * 8 + 1], uvp[u * 8 + 5]);
            acc[u][2] = fmaf(xt, uvp[u * 8 + 2], uvp[u * 8 + 6]);
            acc[u][3] = fmaf(xt, uvp[u * 8 + 3], uvp[u * 8 + 7]);
        }
#pragma unroll
        for (int j4 = 0; j4 < 8; ++j4) {
            const float hv0 = sH0[p][lane][4 * j4 + 0];
            const float hv1 = sH0[p][lane][4 * j4 + 1];
            const float hv2 = sH0[p][lane][4 * j4 + 2];
            const float hv3 = sH0[p][lane][4 * j4 + 3];
            const float* wp = ws + OFF_W0 + (wv * 8 + j4) * 128;
#pragma unroll
            for (int u = 0; u < 8; ++u) {
#pragma unroll
                for (int g = 0; g < 4; ++g) {
                    const float* q = wp + u * 16 + g * 4;
                    float a = acc[u][g];
                    a = fmaf(q[0], hv0, a);
                    a = fmaf(q[1], hv1, a);
                    a = fmaf(q[2], hv2, a);
                    a = fmaf(q[3], hv3, a);
                    acc[u][g] = a;
                }
            }
        }
#pragma unroll
        for (int u = 0; u < 8; ++u) {
            const float gi = sigm(acc[u][0]);
            const float gf = sigm(acc[u][1]);
            const float gg = tanh_fast(acc[u][2]);
            const float go = sigm(acc[u][3]);
            const float cc = fmaf(gf, c0[u], gi * gg);
            c0[u] = cc;
            sH0[np][lane][K0 + u] = go * tanh_fast(cc);
        }
        __syncthreads();   // h0[t] visible to all waves

        // ---------------- layer 1 ----------------
#pragma unroll
        for (int u = 0; u < 8; ++u) {
            acc[u][0] = b1p[u * 4 + 0];
            acc[u][1] = b1p[u * 4 + 1];
            acc[u][2] = b1p[u * 4 + 2];
            acc[u][3] = b1p[u * 4 + 3];
        }
#pragma unroll
        for (int j4 = 0; j4 < 16; ++j4) {
            const float* hsrc = (j4 < 8) ? &sH0[np][lane][4 * j4]
                                         : &sH1[p][lane][4 * (j4 - 8)];
            const float hv0 = hsrc[0];
            const float hv1 = hsrc[1];
            const float hv2 = hsrc[2];
            const float hv3 = hsrc[3];
            const float* wp = ws + OFF_W1 + (wv * 16 + j4) * 128;
#pragma unroll
            for (int u = 0; u < 8; ++u) {
#pragma unroll
                for (int g = 0; g < 4; ++g) {
                    const float* q = wp + u * 16 + g * 4;
                    float a = acc[u][g];
                    a = fmaf(q[0], hv0, a);
                    a = fmaf(q[1], hv1, a);
                    a = fmaf(q[2], hv2, a);
                    a = fmaf(q[3], hv3, a);
                    acc[u][g] = a;
                }
            }
        }
#pragma unroll
        for (int u = 0; u < 8; ++u) {
            const float gi = sigm(acc[u][0]);
            const float gf = sigm(acc[u][1]);
            const float gg = tanh_fast(acc[u][2]);
            const float go = sigm(acc[u][3]);
            const float cc = fmaf(gf, c1[u], gi * gg);
            c1[u] = cc;
            sH1[np][lane][K0 + u] = go * tanh_fast(cc);
        }
        __syncthreads();   // h1[t] visible (also protects next step's reuse)
    }

    // ---------------- fc head: wave 0 only (final h1 is in parity-0 buffer) ----
    if (wv == 0 && valid) {
        float acc2 = ws[OFF_BFC2];
#pragma unroll
        for (int m = 0; m < 16; ++m) {
            const float* fp = ws + OFF_FC1 + m * 32;
            float y = ws[OFF_BFC1 + m];
#pragma unroll
            for (int j = 0; j < 32; ++j)
                y = fmaf(fp[j], sH1[0][lane][j], y);
            acc2 = fmaf(fmaxf(y, 0.f), ws[OFF_FC2 + m], acc2);
        }
        out[node] = acc2;
    }
}

extern "C" void kernel_launch(void* const* d_in, const int* in_sizes, int n_in,
                              void* d_out, int out_size, void* d_ws, size_t ws_size,
                              hipStream_t stream) {
    (void)in_sizes; (void)n_in; (void)out_size; (void)ws_size;
    const float* x    = (const float*)d_in[0];
    // d_in[1] edge_index and d_in[2..9] (GCN weights) are dead code in the reference
    const float* Wtp  = (const float*)d_in[10];
    const float* btp  = (const float*)d_in[11];
    const float* Wih0 = (const float*)d_in[12];
    const float* Whh0 = (const float*)d_in[13];
    const float* bih0 = (const float*)d_in[14];
    const float* bhh0 = (const float*)d_in[15];
    const float* Wih1 = (const float*)d_in[16];
    const float* Whh1 = (const float*)d_in[17];
    const float* bih1 = (const float*)d_in[18];
    const float* bhh1 = (const float*)d_in[19];
    const float* Wfc1 = (const float*)d_in[20];
    const float* bfc1 = (const float*)d_in[21];
    const float* Wfc2 = (const float*)d_in[22];
    const float* bfc2 = (const float*)d_in[23];
    float* ws  = (float*)d_ws;
    float* out = (float*)d_out;

    hipLaunchKernelGGL(repack, dim3(1), dim3(256), 0, stream,
                       Wtp, btp, Wih0, Whh0, bih0, bhh0,
                       Wih1, Whh1, bih1, bhh1, Wfc1, bfc1, Wfc2, bfc2, ws);
    hipLaunchKernelGGL(lstm_main, dim3((NN + 63) / 64), dim3(256), 0, stream,
                       x, ws, out);
}

// Round 6
// 931.819 us; speedup vs baseline: 2.1150x; 1.1490x over previous
//
#include <hip/hip_runtime.h>

#define NN  100000
#define SEQ 12

// d_ws float offsets (repacked weights)
#define OFF_UV   0        // [32][8]: k*8 + {u_i,u_f,u_g,u_o, v_i,v_f,v_g,v_o}
#define OFF_W0   256      // [8][8][64]:  (wave, j4, u*16+g*4+jj)  layer-0 Whh, wave owns 4 units
#define OFF_W1   4352     // [8][16][64]: (wave, j4, u*16+g*4+jj)  [Wih1|Whh1]
#define OFF_B1   12544    // [32][4]      bih1+bhh1
#define OFF_FC1  12672    // [16][32]     W_fc1 transposed
#define OFF_BFC1 13184    // [16]
#define OFF_FC2  13200    // [16]
#define OFF_BFC2 13216    // [1]

__device__ __forceinline__ float rcp_fast(float v) { return __builtin_amdgcn_rcpf(v); }
__device__ __forceinline__ float sigm(float v) { return rcp_fast(1.0f + __expf(-v)); }
__device__ __forceinline__ float tanh_fast(float v) {
    return fmaf(-2.0f, rcp_fast(1.0f + __expf(2.0f * v)), 1.0f);
}

// One-block repack: fold temporal_proj into layer-0 input projection; lay all
// LSTM weights out in the main kernel's exact scalar consumption order
// (wave owns 4 units now).
__global__ void repack(const float* __restrict__ Wtp,  const float* __restrict__ btp,
                       const float* __restrict__ Wih0, const float* __restrict__ Whh0,
                       const float* __restrict__ bih0, const float* __restrict__ bhh0,
                       const float* __restrict__ Wih1, const float* __restrict__ Whh1,
                       const float* __restrict__ bih1, const float* __restrict__ bhh1,
                       const float* __restrict__ Wfc1, const float* __restrict__ bfc1,
                       const float* __restrict__ Wfc2, const float* __restrict__ bfc2,
                       float* __restrict__ ws)
{
    const int tid = threadIdx.x;  // 256 threads
    if (tid < 128) {
        int k = tid >> 2, g = tid & 3;
        int r = g * 32 + k;                 // PyTorch gate-major row (i,f,g,o)
        float u = 0.f, v = 0.f;
        for (int d = 0; d < 16; ++d) {
            u = fmaf(Wih0[r * 16 + d], Wtp[d], u);
            v = fmaf(Wih0[r * 16 + d], btp[d], v);
        }
        ws[OFF_UV + k * 8 + g]     = u;
        ws[OFF_UV + k * 8 + 4 + g] = v + bih0[r] + bhh0[r];
        ws[OFF_B1 + tid]           = bih1[r] + bhh1[r];   // [k*4+g]
    }
    for (int idx = tid; idx < 4096; idx += 256) {
        int w = idx >> 9, rem = idx & 511;
        int j4 = rem >> 6, rem2 = rem & 63;
        int u = rem2 >> 4, g = (rem2 >> 2) & 3, jj = rem2 & 3;
        int K = w * 4 + u, r = g * 32 + K;
        ws[OFF_W0 + idx] = Whh0[r * 32 + j4 * 4 + jj];
    }
    for (int idx = tid; idx < 8192; idx += 256) {
        int w = idx >> 10, rem = idx & 1023;
        int j4 = rem >> 6, rem2 = rem & 63;
        int u = rem2 >> 4, g = (rem2 >> 2) & 3, jj = rem2 & 3;
        int K = w * 4 + u, r = g * 32 + K;
        ws[OFF_W1 + idx] = (j4 < 8) ? Wih1[r * 32 + j4 * 4 + jj]
                                    : Whh1[r * 32 + (j4 - 8) * 4 + jj];
    }
    for (int idx = tid; idx < 512; idx += 256) {
        int m = idx >> 5, j = idx & 31;
        ws[OFF_FC1 + idx] = Wfc1[j * 16 + m];
    }
    if (tid < 16) { ws[OFF_BFC1 + tid] = bfc1[tid]; ws[OFF_FC2 + tid] = Wfc2[tid]; }
    if (tid == 0) ws[OFF_BFC2] = bfc2[0];
}

// 128 nodes per block, 8 waves; wave w owns units [4w,4w+4) of both layers;
// lane l handles nodes l and l+64 (2 nodes/lane: each s_loaded weight feeds
// 2 FMAs -> per-CU weight-stream demand halves vs R5, and 2 independent acc
// chains double latency tolerance; R5 evidence: waves stalled ~85% on the
// wave-uniform weight stream from L2).
// LDS = 67584 B -> 2 blocks/CU -> 16 waves/CU -> 4 waves/EU -> 128-VGPR
// allocator budget (R1/R4/R5 rule). Live regs ~90: no spills.
__global__ __launch_bounds__(512)
void lstm_main(const float* __restrict__ x, const float* __restrict__ ws,
               float* __restrict__ out)
{
    __shared__ float sH0[2][128][33];
    __shared__ float sH1[2][128][33];

    const int tid  = threadIdx.x;
    const int lane = tid & 63;
    const int wv   = __builtin_amdgcn_readfirstlane(tid >> 6);  // wave id 0..7
    const int nA   = blockIdx.x * 128 + lane;
    const int nB   = nA + 64;
    const bool vA  = nA < NN, vB = nB < NN;
    const int xa   = vA ? nA : 0, xb = vB ? nB : 0;
    const int K0   = wv * 4;                 // owned units [K0, K0+4)
    const int rA   = lane, rB = lane + 64;   // LDS rows for the two nodes

    float cA0[4], cA1[4], cB0[4], cB1[4];
#pragma unroll
    for (int u = 0; u < 4; ++u) {
        cA0[u] = 0.f; cA1[u] = 0.f; cB0[u] = 0.f; cB1[u] = 0.f;
        sH0[0][rA][K0 + u] = 0.f; sH0[0][rB][K0 + u] = 0.f;
        sH1[0][rA][K0 + u] = 0.f; sH1[0][rB][K0 + u] = 0.f;
    }
    __syncthreads();

    const float* uvp = ws + OFF_UV + K0 * 8;   // uniform -> s_load
    const float* b1p = ws + OFF_B1 + K0 * 4;

    float xtA = x[(size_t)xa * 32 + 20];
    float xtB = x[(size_t)xb * 32 + 20];

#pragma unroll 1
    for (int t = 0; t < SEQ; ++t) {
        const int p = t & 1, np = p ^ 1;
        const float xA = xtA, xB = xtB;
        if (t + 1 < SEQ) {
            xtA = x[(size_t)xa * 32 + 21 + t];
            xtB = x[(size_t)xb * 32 + 21 + t];
        }

        float aA[4][4], aB[4][4];

        // ---------------- layer 0 ----------------
#pragma unroll
        for (int u = 0; u < 4; ++u)
#pragma unroll
            for (int g = 0; g < 4; ++g) {
                const float uu = uvp[u * 8 + g], vv = uvp[u * 8 + 4 + g];
                aA[u][g] = fmaf(xA, uu, vv);
                aB[u][g] = fmaf(xB, uu, vv);
            }
#pragma unroll
        for (int j4 = 0; j4 < 8; ++j4) {
            const float hA0 = sH0[p][rA][4 * j4 + 0];
            const float hA1 = sH0[p][rA][4 * j4 + 1];
            const float hA2 = sH0[p][rA][4 * j4 + 2];
            const float hA3 = sH0[p][rA][4 * j4 + 3];
            const float hB0 = sH0[p][rB][4 * j4 + 0];
            const float hB1 = sH0[p][rB][4 * j4 + 1];
            const float hB2 = sH0[p][rB][4 * j4 + 2];
            const float hB3 = sH0[p][rB][4 * j4 + 3];
            const float* wp = ws + OFF_W0 + (wv * 8 + j4) * 64;
#pragma unroll
            for (int u = 0; u < 4; ++u)
#pragma unroll
                for (int g = 0; g < 4; ++g) {
                    const float* q = wp + u * 16 + g * 4;
                    float a = aA[u][g], b = aB[u][g];
                    a = fmaf(q[0], hA0, a); b = fmaf(q[0], hB0, b);
                    a = fmaf(q[1], hA1, a); b = fmaf(q[1], hB1, b);
                    a = fmaf(q[2], hA2, a); b = fmaf(q[2], hB2, b);
                    a = fmaf(q[3], hA3, a); b = fmaf(q[3], hB3, b);
                    aA[u][g] = a; aB[u][g] = b;
                }
        }
#pragma unroll
        for (int u = 0; u < 4; ++u) {
            float gi = sigm(aA[u][0]), gf = sigm(aA[u][1]);
            float gg = tanh_fast(aA[u][2]), go = sigm(aA[u][3]);
            float cc = fmaf(gf, cA0[u], gi * gg);
            cA0[u] = cc;
            sH0[np][rA][K0 + u] = go * tanh_fast(cc);
            gi = sigm(aB[u][0]); gf = sigm(aB[u][1]);
            gg = tanh_fast(aB[u][2]); go = sigm(aB[u][3]);
            cc = fmaf(gf, cB0[u], gi * gg);
            cB0[u] = cc;
            sH0[np][rB][K0 + u] = go * tanh_fast(cc);
        }
        __syncthreads();   // h0[t] visible to all waves

        // ---------------- layer 1 ----------------
#pragma unroll
        for (int u = 0; u < 4; ++u)
#pragma unroll
            for (int g = 0; g < 4; ++g) {
                const float bb = b1p[u * 4 + g];
                aA[u][g] = bb; aB[u][g] = bb;
            }
#pragma unroll
        for (int j4 = 0; j4 < 16; ++j4) {
            const float* hsA = (j4 < 8) ? &sH0[np][rA][4 * j4] : &sH1[p][rA][4 * (j4 - 8)];
            const float* hsB = (j4 < 8) ? &sH0[np][rB][4 * j4] : &sH1[p][rB][4 * (j4 - 8)];
            const float hA0 = hsA[0], hA1 = hsA[1], hA2 = hsA[2], hA3 = hsA[3];
            const float hB0 = hsB[0], hB1 = hsB[1], hB2 = hsB[2], hB3 = hsB[3];
            const float* wp = ws + OFF_W1 + (wv * 16 + j4) * 64;
#pragma unroll
            for (int u = 0; u < 4; ++u)
#pragma unroll
                for (int g = 0; g < 4; ++g) {
                    const float* q = wp + u * 16 + g * 4;
                    float a = aA[u][g], b = aB[u][g];
                    a = fmaf(q[0], hA0, a); b = fmaf(q[0], hB0, b);
                    a = fmaf(q[1], hA1, a); b = fmaf(q[1], hB1, b);
                    a = fmaf(q[2], hA2, a); b = fmaf(q[2], hB2, b);
                    a = fmaf(q[3], hA3, a); b = fmaf(q[3], hB3, b);
                    aA[u][g] = a; aB[u][g] = b;
                }
        }
#pragma unroll
        for (int u = 0; u < 4; ++u) {
            float gi = sigm(aA[u][0]), gf = sigm(aA[u][1]);
            float gg = tanh_fast(aA[u][2]), go = sigm(aA[u][3]);
            float cc = fmaf(gf, cA1[u], gi * gg);
            cA1[u] = cc;
            sH1[np][rA][K0 + u] = go * tanh_fast(cc);
            gi = sigm(aB[u][0]); gf = sigm(aB[u][1]);
            gg = tanh_fast(aB[u][2]); go = sigm(aB[u][3]);
            cc = fmaf(gf, cB1[u], gi * gg);
            cB1[u] = cc;
            sH1[np][rB][K0 + u] = go * tanh_fast(cc);
        }
        __syncthreads();   // h1[t] visible
    }

    // -------- fc head: wave 0 does both nodes (final h1 in parity-0 buffer) ----
    if (wv == 0) {
#pragma unroll
        for (int nn = 0; nn < 2; ++nn) {
            const int node = nn ? nB : nA;
            const int row  = nn ? rB : rA;
            if (node < NN) {
                float acc2 = ws[OFF_BFC2];
#pragma unroll
                for (int m = 0; m < 16; ++m) {
                    const float* fp = ws + OFF_FC1 + m * 32;
                    float y = ws[OFF_BFC1 + m];
#pragma unroll
                    for (int j = 0; j < 32; ++j)
                        y = fmaf(fp[j], sH1[0][row][j], y);
                    acc2 = fmaf(fmaxf(y, 0.f), ws[OFF_FC2 + m], acc2);
                }
                out[node] = acc2;
            }
        }
    }
}

extern "C" void kernel_launch(void* const* d_in, const int* in_sizes, int n_in,
                              void* d_out, int out_size, void* d_ws, size_t ws_size,
                              hipStream_t stream) {
    (void)in_sizes; (void)n_in; (void)out_size; (void)ws_size;
    const float* x    = (const float*)d_in[0];
    // d_in[1] edge_index and d_in[2..9] (GCN weights) are dead code in the reference
    const float* Wtp  = (const float*)d_in[10];
    const float* btp  = (const float*)d_in[11];
    const float* Wih0 = (const float*)d_in[12];
    const float* Whh0 = (const float*)d_in[13];
    const float* bih0 = (const float*)d_in[14];
    const float* bhh0 = (const float*)d_in[15];
    const float* Wih1 = (const float*)d_in[16];
    const float* Whh1 = (const float*)d_in[17];
    const float* bih1 = (const float*)d_in[18];
    const float* bhh1 = (const float*)d_in[19];
    const float* Wfc1 = (const float*)d_in[20];
    const float* bfc1 = (const float*)d_in[21];
    const float* Wfc2 = (const float*)d_in[22];
    const float* bfc2 = (const float*)d_in[23];
    float* ws  = (float*)d_ws;
    float* out = (float*)d_out;

    hipLaunchKernelGGL(repack, dim3(1), dim3(256), 0, stream,
                       Wtp, btp, Wih0, Whh0, bih0, bhh0,
                       Wih1, Whh1, bih1, bhh1, Wfc1, bfc1, Wfc2, bfc2, ws);
    hipLaunchKernelGGL(lstm_main, dim3((NN + 127) / 128), dim3(512), 0, stream,
                       x, ws, out);
}

// Round 7
// 929.172 us; speedup vs baseline: 2.1210x; 1.0028x over previous
//
#include <hip/hip_runtime.h>

#define NN   100000
#define SEQ  12
#define HSTR 36   // LDS row stride (floats): 144 B -> 16B-aligned float4 reads, even bank spread

// d_ws float offsets (repacked weights)
#define OFF_UV   0        // [32][8]: k*8 + {u_i,u_f,u_g,u_o, v_i,v_f,v_g,v_o}
#define OFF_W0   256      // [16][8][32]:  (wave, j4, u*16+g*4+jj)  layer-0 Whh, wave owns 2 units
#define OFF_W1   4352     // [16][16][32]: (wave, j4, u*16+g*4+jj)  [Wih1|Whh1]
#define OFF_B1   12544    // [32][4]       bih1+bhh1
#define OFF_FC1  12672    // [16][32]      W_fc1 transposed
#define OFF_BFC1 13184    // [16]
#define OFF_FC2  13200    // [16]
#define OFF_BFC2 13216    // [1]

__device__ __forceinline__ float rcp_fast(float v) { return __builtin_amdgcn_rcpf(v); }
__device__ __forceinline__ float sigm(float v) { return rcp_fast(1.0f + __expf(-v)); }
__device__ __forceinline__ float tanh_fast(float v) {
    return fmaf(-2.0f, rcp_fast(1.0f + __expf(2.0f * v)), 1.0f);
}

// One-block repack: fold temporal_proj into layer-0 input projection; lay all
// LSTM weights out in the main kernel's exact scalar consumption order
// (wave owns 2 units).
__global__ void repack(const float* __restrict__ Wtp,  const float* __restrict__ btp,
                       const float* __restrict__ Wih0, const float* __restrict__ Whh0,
                       const float* __restrict__ bih0, const float* __restrict__ bhh0,
                       const float* __restrict__ Wih1, const float* __restrict__ Whh1,
                       const float* __restrict__ bih1, const float* __restrict__ bhh1,
                       const float* __restrict__ Wfc1, const float* __restrict__ bfc1,
                       const float* __restrict__ Wfc2, const float* __restrict__ bfc2,
                       float* __restrict__ ws)
{
    const int tid = threadIdx.x;  // 256 threads
    if (tid < 128) {
        int k = tid >> 2, g = tid & 3;
        int r = g * 32 + k;                 // PyTorch gate-major row (i,f,g,o)
        float u = 0.f, v = 0.f;
        for (int d = 0; d < 16; ++d) {
            u = fmaf(Wih0[r * 16 + d], Wtp[d], u);
            v = fmaf(Wih0[r * 16 + d], btp[d], v);
        }
        ws[OFF_UV + k * 8 + g]     = u;
        ws[OFF_UV + k * 8 + 4 + g] = v + bih0[r] + bhh0[r];
        ws[OFF_B1 + tid]           = bih1[r] + bhh1[r];   // [k*4+g]
    }
    for (int idx = tid; idx < 4096; idx += 256) {
        int w = idx >> 8, rem = idx & 255;
        int j4 = rem >> 5, rem2 = rem & 31;
        int u = rem2 >> 4, g = (rem2 >> 2) & 3, jj = rem2 & 3;
        int K = w * 2 + u, r = g * 32 + K;
        ws[OFF_W0 + idx] = Whh0[r * 32 + j4 * 4 + jj];
    }
    for (int idx = tid; idx < 8192; idx += 256) {
        int w = idx >> 9, rem = idx & 511;
        int j4 = rem >> 5, rem2 = rem & 31;
        int u = rem2 >> 4, g = (rem2 >> 2) & 3, jj = rem2 & 3;
        int K = w * 2 + u, r = g * 32 + K;
        ws[OFF_W1 + idx] = (j4 < 8) ? Wih1[r * 32 + j4 * 4 + jj]
                                    : Whh1[r * 32 + (j4 - 8) * 4 + jj];
    }
    for (int idx = tid; idx < 512; idx += 256) {
        int m = idx >> 5, j = idx & 31;
        ws[OFF_FC1 + idx] = Wfc1[j * 16 + m];
    }
    if (tid < 16) { ws[OFF_BFC1 + tid] = bfc1[tid]; ws[OFF_FC2 + tid] = Wfc2[tid]; }
    if (tid == 0) ws[OFF_BFC2] = bfc2[0];
}

// 128 nodes/block, 16 waves of 64 lanes (1024 thr); wave w owns units
// [2w, 2w+2) of both layers; lane l handles nodes l and l+64.
// Each s_loaded weight feeds 2 FMAs; weight stream = 3 KB/wave-step (4x less
// than R5 per CU-step). Live regs ~45: SPILL-PROOF even at the allocator's
// worst observed cap of 64 (R4/R6 evidence; the LDS->budget model is
// unreliable, so design under 64 instead of fighting it).
// LDS 73728 B -> 2 blocks/CU -> 32 waves/CU -> 8 waves/SIMD: 2x R5's
// latency-hiding depth. HSTR=36 -> 16B-aligned ds_read_b128, even bank use.
__global__ __launch_bounds__(1024)
void lstm_main(const float* __restrict__ x, const float* __restrict__ ws,
               float* __restrict__ out)
{
    __shared__ __align__(16) float sH0[2][128][HSTR];
    __shared__ __align__(16) float sH1[2][128][HSTR];

    const int tid  = threadIdx.x;
    const int lane = tid & 63;
    const int wv   = __builtin_amdgcn_readfirstlane(tid >> 6);  // wave id 0..15
    const int nA   = blockIdx.x * 128 + lane;
    const int nB   = nA + 64;
    const int xa   = (nA < NN) ? nA : 0;
    const int xb   = (nB < NN) ? nB : 0;
    const int K0   = wv * 2;                 // owned units [K0, K0+2)
    const int rA   = lane, rB = lane + 64;   // LDS rows for the two nodes

    float cA0[2], cB0[2], cA1[2], cB1[2];
#pragma unroll
    for (int u = 0; u < 2; ++u) {
        cA0[u] = 0.f; cB0[u] = 0.f; cA1[u] = 0.f; cB1[u] = 0.f;
        sH0[0][rA][K0 + u] = 0.f; sH0[0][rB][K0 + u] = 0.f;
        sH1[0][rA][K0 + u] = 0.f; sH1[0][rB][K0 + u] = 0.f;
    }
    __syncthreads();

    const float* uvp = ws + OFF_UV + K0 * 8;   // uniform -> s_load (hoisted)
    const float* b1p = ws + OFF_B1 + K0 * 4;

    float xtA = x[(size_t)xa * 32 + 20];
    float xtB = x[(size_t)xb * 32 + 20];

#pragma unroll 1
    for (int t = 0; t < SEQ; ++t) {
        const int p = t & 1, np = p ^ 1;
        const float xA = xtA, xB = xtB;
        if (t + 1 < SEQ) {
            xtA = x[(size_t)xa * 32 + 21 + t];
            xtB = x[(size_t)xb * 32 + 21 + t];
        }

        float aA[2][4], aB[2][4];

        // ---------------- layer 0 ----------------
#pragma unroll
        for (int u = 0; u < 2; ++u)
#pragma unroll
            for (int g = 0; g < 4; ++g) {
                const float uu = uvp[u * 8 + g], vv = uvp[u * 8 + 4 + g];
                aA[u][g] = fmaf(xA, uu, vv);
                aB[u][g] = fmaf(xB, uu, vv);
            }
#pragma unroll
        for (int j4 = 0; j4 < 8; ++j4) {
            const float4 hA = *(const float4*)&sH0[p][rA][4 * j4];
            const float4 hB = *(const float4*)&sH0[p][rB][4 * j4];
            const float* wp = ws + OFF_W0 + (wv * 8 + j4) * 32;
#pragma unroll
            for (int u = 0; u < 2; ++u)
#pragma unroll
                for (int g = 0; g < 4; ++g) {
                    const float* q = wp + u * 16 + g * 4;
                    float a = aA[u][g], b = aB[u][g];
                    a = fmaf(q[0], hA.x, a); b = fmaf(q[0], hB.x, b);
                    a = fmaf(q[1], hA.y, a); b = fmaf(q[1], hB.y, b);
                    a = fmaf(q[2], hA.z, a); b = fmaf(q[2], hB.z, b);
                    a = fmaf(q[3], hA.w, a); b = fmaf(q[3], hB.w, b);
                    aA[u][g] = a; aB[u][g] = b;
                }
        }
#pragma unroll
        for (int u = 0; u < 2; ++u) {
            float gi = sigm(aA[u][0]), gf = sigm(aA[u][1]);
            float gg = tanh_fast(aA[u][2]), go = sigm(aA[u][3]);
            float cc = fmaf(gf, cA0[u], gi * gg);
            cA0[u] = cc;
            sH0[np][rA][K0 + u] = go * tanh_fast(cc);
            gi = sigm(aB[u][0]); gf = sigm(aB[u][1]);
            gg = tanh_fast(aB[u][2]); go = sigm(aB[u][3]);
            cc = fmaf(gf, cB0[u], gi * gg);
            cB0[u] = cc;
            sH0[np][rB][K0 + u] = go * tanh_fast(cc);
        }
        __syncthreads();   // h0[t] visible to all waves

        // ---------------- layer 1 ----------------
#pragma unroll
        for (int u = 0; u < 2; ++u)
#pragma unroll
            for (int g = 0; g < 4; ++g) {
                const float bb = b1p[u * 4 + g];
                aA[u][g] = bb; aB[u][g] = bb;
            }
#pragma unroll
        for (int j4 = 0; j4 < 16; ++j4) {
            const float4 hA = (j4 < 8) ? *(const float4*)&sH0[np][rA][4 * j4]
                                       : *(const float4*)&sH1[p][rA][4 * (j4 - 8)];
            const float4 hB = (j4 < 8) ? *(const float4*)&sH0[np][rB][4 * j4]
                                       : *(const float4*)&sH1[p][rB][4 * (j4 - 8)];
            const float* wp = ws + OFF_W1 + (wv * 16 + j4) * 32;
#pragma unroll
            for (int u = 0; u < 2; ++u)
#pragma unroll
                for (int g = 0; g < 4; ++g) {
                    const float* q = wp + u * 16 + g * 4;
                    float a = aA[u][g], b = aB[u][g];
                    a = fmaf(q[0], hA.x, a); b = fmaf(q[0], hB.x, b);
                    a = fmaf(q[1], hA.y, a); b = fmaf(q[1], hB.y, b);
                    a = fmaf(q[2], hA.z, a); b = fmaf(q[2], hB.z, b);
                    a = fmaf(q[3], hA.w, a); b = fmaf(q[3], hB.w, b);
                    aA[u][g] = a; aB[u][g] = b;
                }
        }
#pragma unroll
        for (int u = 0; u < 2; ++u) {
            float gi = sigm(aA[u][0]), gf = sigm(aA[u][1]);
            float gg = tanh_fast(aA[u][2]), go = sigm(aA[u][3]);
            float cc = fmaf(gf, cA1[u], gi * gg);
            cA1[u] = cc;
            sH1[np][rA][K0 + u] = go * tanh_fast(cc);
            gi = sigm(aB[u][0]); gf = sigm(aB[u][1]);
            gg = tanh_fast(aB[u][2]); go = sigm(aB[u][3]);
            cc = fmaf(gf, cB1[u], gi * gg);
            cB1[u] = cc;
            sH1[np][rB][K0 + u] = go * tanh_fast(cc);
        }
        __syncthreads();   // h1[t] visible
    }

    // -------- fc head: wave 0 does both nodes (final h1 in parity-0 buffer) ----
    if (wv == 0) {
#pragma unroll
        for (int nn = 0; nn < 2; ++nn) {
            const int node = nn ? nB : nA;
            const int row  = nn ? rB : rA;
            if (node < NN) {
                float acc2 = ws[OFF_BFC2];
#pragma unroll
                for (int m = 0; m < 16; ++m) {
                    const float* fp = ws + OFF_FC1 + m * 32;
                    float y = ws[OFF_BFC1 + m];
#pragma unroll
                    for (int j = 0; j < 32; ++j)
                        y = fmaf(fp[j], sH1[0][row][j], y);
                    acc2 = fmaf(fmaxf(y, 0.f), ws[OFF_FC2 + m], acc2);
                }
                out[node] = acc2;
            }
        }
    }
}

extern "C" void kernel_launch(void* const* d_in, const int* in_sizes, int n_in,
                              void* d_out, int out_size, void* d_ws, size_t ws_size,
                              hipStream_t stream) {
    (void)in_sizes; (void)n_in; (void)out_size; (void)ws_size;
    const float* x    = (const float*)d_in[0];
    // d_in[1] edge_index and d_in[2..9] (GCN weights) are dead code in the reference
    const float* Wtp  = (const float*)d_in[10];
    const float* btp  = (const float*)d_in[11];
    const float* Wih0 = (const float*)d_in[12];
    const float* Whh0 = (const float*)d_in[13];
    const float* bih0 = (const float*)d_in[14];
    const float* bhh0 = (const float*)d_in[15];
    const float* Wih1 = (const float*)d_in[16];
    const float* Whh1 = (const float*)d_in[17];
    const float* bih1 = (const float*)d_in[18];
    const float* bhh1 = (const float*)d_in[19];
    const float* Wfc1 = (const float*)d_in[20];
    const float* bfc1 = (const float*)d_in[21];
    const float* Wfc2 = (const float*)d_in[22];
    const float* bfc2 = (const float*)d_in[23];
    float* ws  = (float*)d_ws;
    float* out = (float*)d_out;

    hipLaunchKernelGGL(repack, dim3(1), dim3(256), 0, stream,
                       Wtp, btp, Wih0, Whh0, bih0, bhh0,
                       Wih1, Whh1, bih1, bhh1, Wfc1, bfc1, Wfc2, bfc2, ws);
    hipLaunchKernelGGL(lstm_main, dim3((NN + 127) / 128), dim3(1024), 0, stream,
                       x, ws, out);
}

// Round 8
// 548.766 us; speedup vs baseline: 3.5914x; 1.6932x over previous
//
#include <hip/hip_runtime.h>

#define NN   100000
#define SEQ  12
#define HSTR 36   // LDS h-row stride (floats): 144 B -> 16B-aligned float4 reads

// weight-block float offsets (d_ws layout from repack; mirrored 1:1 into LDS)
#define OFF_UV   0        // [32][8]: k*8 + {u_i,u_f,u_g,u_o, v_i,v_f,v_g,v_o}
#define OFF_W0   256      // [16][8][32]:  (wave, j4, u*16+g*4+jj)  layer-0 Whh, wave owns 2 units
#define OFF_W1   4352     // [16][16][32]: (wave, j4, u*16+g*4+jj)  [Wih1|Whh1]
#define OFF_B1   12544    // [32][4]       bih1+bhh1
#define OFF_FC1  12672    // [16][32]      W_fc1 transposed
#define OFF_BFC1 13184    // [16]
#define OFF_FC2  13200    // [16]
#define OFF_BFC2 13216    // [1]
#define W_TOTAL  13217

__device__ __forceinline__ float rcp_fast(float v) { return __builtin_amdgcn_rcpf(v); }
__device__ __forceinline__ float sigm(float v) { return rcp_fast(1.0f + __expf(-v)); }
__device__ __forceinline__ float tanh_fast(float v) {
    return fmaf(-2.0f, rcp_fast(1.0f + __expf(2.0f * v)), 1.0f);
}

// One-block repack: fold temporal_proj into layer-0 input projection; lay all
// LSTM weights out in the main kernel's exact consumption order (wave owns 2 units).
__global__ void repack(const float* __restrict__ Wtp,  const float* __restrict__ btp,
                       const float* __restrict__ Wih0, const float* __restrict__ Whh0,
                       const float* __restrict__ bih0, const float* __restrict__ bhh0,
                       const float* __restrict__ Wih1, const float* __restrict__ Whh1,
                       const float* __restrict__ bih1, const float* __restrict__ bhh1,
                       const float* __restrict__ Wfc1, const float* __restrict__ bfc1,
                       const float* __restrict__ Wfc2, const float* __restrict__ bfc2,
                       float* __restrict__ ws)
{
    const int tid = threadIdx.x;  // 256 threads
    if (tid < 128) {
        int k = tid >> 2, g = tid & 3;
        int r = g * 32 + k;                 // PyTorch gate-major row (i,f,g,o)
        float u = 0.f, v = 0.f;
        for (int d = 0; d < 16; ++d) {
            u = fmaf(Wih0[r * 16 + d], Wtp[d], u);
            v = fmaf(Wih0[r * 16 + d], btp[d], v);
        }
        ws[OFF_UV + k * 8 + g]     = u;
        ws[OFF_UV + k * 8 + 4 + g] = v + bih0[r] + bhh0[r];
        ws[OFF_B1 + tid]           = bih1[r] + bhh1[r];   // [k*4+g]
    }
    for (int idx = tid; idx < 4096; idx += 256) {
        int w = idx >> 8, rem = idx & 255;
        int j4 = rem >> 5, rem2 = rem & 31;
        int u = rem2 >> 4, g = (rem2 >> 2) & 3, jj = rem2 & 3;
        int K = w * 2 + u, r = g * 32 + K;
        ws[OFF_W0 + idx] = Whh0[r * 32 + j4 * 4 + jj];
    }
    for (int idx = tid; idx < 8192; idx += 256) {
        int w = idx >> 9, rem = idx & 511;
        int j4 = rem >> 5, rem2 = rem & 31;
        int u = rem2 >> 4, g = (rem2 >> 2) & 3, jj = rem2 & 3;
        int K = w * 2 + u, r = g * 32 + K;
        ws[OFF_W1 + idx] = (j4 < 8) ? Wih1[r * 32 + j4 * 4 + jj]
                                    : Whh1[r * 32 + (j4 - 8) * 4 + jj];
    }
    for (int idx = tid; idx < 512; idx += 256) {
        int m = idx >> 5, j = idx & 31;
        ws[OFF_FC1 + idx] = Wfc1[j * 16 + m];
    }
    if (tid < 16) { ws[OFF_BFC1 + tid] = bfc1[tid]; ws[OFF_FC2 + tid] = Wfc2[tid]; }
    if (tid == 0) ws[OFF_BFC2] = bfc2[0];
}

// 128 nodes/block, 16 waves; wave w owns units [2w,2w+2); lane l handles
// nodes l and l+64.
// KEY CHANGE vs R7: weights live in LDS and are read as wave-uniform
// BROADCAST ds_reads (same addr across 64 lanes = conflict-free, ~120cy
// pipelineable) instead of s_load streams. R5-R7 evidence: the scalar-path
// weight stream (48-96 KB/CU/step, re-missing the scalar K$ after every
// barrier) stalled all waves in lockstep -- 2x waves and 2x reuse each
// bought only ~15%. LDS total 126.7 KB -> 1 block/CU (16 waves, 4/SIMD).
__global__ __launch_bounds__(1024)
void lstm_main(const float* __restrict__ x, const float* __restrict__ ws,
               float* __restrict__ out)
{
    __shared__ __align__(16) float sw[13232];          // all weights (52.9 KB)
    __shared__ __align__(16) float sH0[2][128][HSTR];  // 36.9 KB
    __shared__ __align__(16) float sH1[2][128][HSTR];  // 36.9 KB

    const int tid  = threadIdx.x;
    const int lane = tid & 63;
    const int wv   = __builtin_amdgcn_readfirstlane(tid >> 6);  // wave id 0..15
    const int nA   = blockIdx.x * 128 + lane;
    const int nB   = nA + 64;
    const int xa   = (nA < NN) ? nA : 0;
    const int xb   = (nB < NN) ? nB : 0;
    const int K0   = wv * 2;                 // owned units [K0, K0+2)
    const int rA   = lane, rB = lane + 64;   // LDS h rows for the two nodes

    // stage all weights into LDS once per block
    for (int i = tid; i < W_TOTAL; i += 1024) sw[i] = ws[i];

    float cA0[2], cB0[2], cA1[2], cB1[2];
#pragma unroll
    for (int u = 0; u < 2; ++u) {
        cA0[u] = 0.f; cB0[u] = 0.f; cA1[u] = 0.f; cB1[u] = 0.f;
        sH0[0][rA][K0 + u] = 0.f; sH0[0][rB][K0 + u] = 0.f;
        sH1[0][rA][K0 + u] = 0.f; sH1[0][rB][K0 + u] = 0.f;
    }
    __syncthreads();

    const float* uvp = sw + OFF_UV + K0 * 8;   // uniform addr -> LDS broadcast
    const float* b1p = sw + OFF_B1 + K0 * 4;

    float xtA = x[(size_t)xa * 32 + 20];
    float xtB = x[(size_t)xb * 32 + 20];

#pragma unroll 1
    for (int t = 0; t < SEQ; ++t) {
        const int p = t & 1, np = p ^ 1;
        const float xA = xtA, xB = xtB;
        if (t + 1 < SEQ) {
            xtA = x[(size_t)xa * 32 + 21 + t];
            xtB = x[(size_t)xb * 32 + 21 + t];
        }

        float aA[2][4], aB[2][4];

        // ---------------- layer 0 ----------------
#pragma unroll
        for (int u = 0; u < 2; ++u)
#pragma unroll
            for (int g = 0; g < 4; ++g) {
                const float uu = uvp[u * 8 + g], vv = uvp[u * 8 + 4 + g];
                aA[u][g] = fmaf(xA, uu, vv);
                aB[u][g] = fmaf(xB, uu, vv);
            }
#pragma unroll
        for (int j4 = 0; j4 < 8; ++j4) {
            const float4 hA = *(const float4*)&sH0[p][rA][4 * j4];
            const float4 hB = *(const float4*)&sH0[p][rB][4 * j4];
            const float* wp = sw + OFF_W0 + (wv * 8 + j4) * 32;
#pragma unroll
            for (int u = 0; u < 2; ++u)
#pragma unroll
                for (int g = 0; g < 4; ++g) {
                    const float4 q = *(const float4*)(wp + u * 16 + g * 4); // broadcast
                    float a = aA[u][g], b = aB[u][g];
                    a = fmaf(q.x, hA.x, a); b = fmaf(q.x, hB.x, b);
                    a = fmaf(q.y, hA.y, a); b = fmaf(q.y, hB.y, b);
                    a = fmaf(q.z, hA.z, a); b = fmaf(q.z, hB.z, b);
                    a = fmaf(q.w, hA.w, a); b = fmaf(q.w, hB.w, b);
                    aA[u][g] = a; aB[u][g] = b;
                }
        }
#pragma unroll
        for (int u = 0; u < 2; ++u) {
            float gi = sigm(aA[u][0]), gf = sigm(aA[u][1]);
            float gg = tanh_fast(aA[u][2]), go = sigm(aA[u][3]);
            float cc = fmaf(gf, cA0[u], gi * gg);
            cA0[u] = cc;
            sH0[np][rA][K0 + u] = go * tanh_fast(cc);
            gi = sigm(aB[u][0]); gf = sigm(aB[u][1]);
            gg = tanh_fast(aB[u][2]); go = sigm(aB[u][3]);
            cc = fmaf(gf, cB0[u], gi * gg);
            cB0[u] = cc;
            sH0[np][rB][K0 + u] = go * tanh_fast(cc);
        }
        __syncthreads();   // h0[t] visible to all waves

        // ---------------- layer 1 ----------------
#pragma unroll
        for (int u = 0; u < 2; ++u)
#pragma unroll
            for (int g = 0; g < 4; ++g) {
                const float bb = b1p[u * 4 + g];
                aA[u][g] = bb; aB[u][g] = bb;
            }
#pragma unroll
        for (int j4 = 0; j4 < 16; ++j4) {
            const float4 hA = (j4 < 8) ? *(const float4*)&sH0[np][rA][4 * j4]
                                       : *(const float4*)&sH1[p][rA][4 * (j4 - 8)];
            const float4 hB = (j4 < 8) ? *(const float4*)&sH0[np][rB][4 * j4]
                                       : *(const float4*)&sH1[p][rB][4 * (j4 - 8)];
            const float* wp = sw + OFF_W1 + (wv * 16 + j4) * 32;
#pragma unroll
            for (int u = 0; u < 2; ++u)
#pragma unroll
                for (int g = 0; g < 4; ++g) {
                    const float4 q = *(const float4*)(wp + u * 16 + g * 4); // broadcast
                    float a = aA[u][g], b = aB[u][g];
                    a = fmaf(q.x, hA.x, a); b = fmaf(q.x, hB.x, b);
                    a = fmaf(q.y, hA.y, a); b = fmaf(q.y, hB.y, b);
                    a = fmaf(q.z, hA.z, a); b = fmaf(q.z, hB.z, b);
                    a = fmaf(q.w, hA.w, a); b = fmaf(q.w, hB.w, b);
                    aA[u][g] = a; aB[u][g] = b;
                }
        }
#pragma unroll
        for (int u = 0; u < 2; ++u) {
            float gi = sigm(aA[u][0]), gf = sigm(aA[u][1]);
            float gg = tanh_fast(aA[u][2]), go = sigm(aA[u][3]);
            float cc = fmaf(gf, cA1[u], gi * gg);
            cA1[u] = cc;
            sH1[np][rA][K0 + u] = go * tanh_fast(cc);
            gi = sigm(aB[u][0]); gf = sigm(aB[u][1]);
            gg = tanh_fast(aB[u][2]); go = sigm(aB[u][3]);
            cc = fmaf(gf, cB1[u], gi * gg);
            cB1[u] = cc;
            sH1[np][rB][K0 + u] = go * tanh_fast(cc);
        }
        __syncthreads();   // h1[t] visible
    }

    // -------- fc head: wave 0 does both nodes (final h1 in parity-0 buffer) ----
    if (wv == 0) {
#pragma unroll
        for (int nn = 0; nn < 2; ++nn) {
            const int node = nn ? nB : nA;
            const int row  = nn ? rB : rA;
            if (node < NN) {
                float acc2 = sw[OFF_BFC2];
#pragma unroll
                for (int m = 0; m < 16; ++m) {
                    const float* fp = sw + OFF_FC1 + m * 32;
                    float y = sw[OFF_BFC1 + m];
#pragma unroll
                    for (int j = 0; j < 32; ++j)
                        y = fmaf(fp[j], sH1[0][row][j], y);
                    acc2 = fmaf(fmaxf(y, 0.f), sw[OFF_FC2 + m], acc2);
                }
                out[node] = acc2;
            }
        }
    }
}

extern "C" void kernel_launch(void* const* d_in, const int* in_sizes, int n_in,
                              void* d_out, int out_size, void* d_ws, size_t ws_size,
                              hipStream_t stream) {
    (void)in_sizes; (void)n_in; (void)out_size; (void)ws_size;
    const float* x    = (const float*)d_in[0];
    // d_in[1] edge_index and d_in[2..9] (GCN weights) are dead code in the reference
    const float* Wtp  = (const float*)d_in[10];
    const float* btp  = (const float*)d_in[11];
    const float* Wih0 = (const float*)d_in[12];
    const float* Whh0 = (const float*)d_in[13];
    const float* bih0 = (const float*)d_in[14];
    const float* bhh0 = (const float*)d_in[15];
    const float* Wih1 = (const float*)d_in[16];
    const float* Whh1 = (const float*)d_in[17];
    const float* bih1 = (const float*)d_in[18];
    const float* bhh1 = (const float*)d_in[19];
    const float* Wfc1 = (const float*)d_in[20];
    const float* bfc1 = (const float*)d_in[21];
    const float* Wfc2 = (const float*)d_in[22];
    const float* bfc2 = (const float*)d_in[23];
    float* ws  = (float*)d_ws;
    float* out = (float*)d_out;

    hipLaunchKernelGGL(repack, dim3(1), dim3(256), 0, stream,
                       Wtp, btp, Wih0, Whh0, bih0, bhh0,
                       Wih1, Whh1, bih1, bhh1, Wfc1, bfc1, Wfc2, bfc2, ws);
    hipLaunchKernelGGL(lstm_main, dim3((NN + 127) / 128), dim3(1024), 0, stream,
                       x, ws, out);
}

// Round 9
// 491.121 us; speedup vs baseline: 4.0129x; 1.1174x over previous
//
#include <hip/hip_runtime.h>

#define NN  100000
#define SEQ 12

// d_ws float offsets (repacked weights; mirrored 1:1 into LDS)
#define OFF_UV   0        // [32][8]: k*8 + {u_i,u_f,u_g,u_o, v_i,v_f,v_g,v_o}
#define OFF_W0   256      // [16][8][32]:  (wave, j4, u*16+g*4+jj)  layer-0 Whh, wave owns 2 units
#define OFF_W1   4352     // [16][16][32]: (wave, j4, u*16+g*4+jj)  [Wih1|Whh1]
#define OFF_B1   12544    // [32][4]       bih1+bhh1
#define OFF_FC1  12672    // [16][32]      W_fc1 transposed
#define OFF_BFC1 13184    // [16]
#define OFF_FC2  13200    // [16]
#define OFF_BFC2 13216    // [1]
#define W_TOTAL  13217

__device__ __forceinline__ float rcp_fast(float v) { return __builtin_amdgcn_rcpf(v); }
__device__ __forceinline__ float sigm(float v) { return rcp_fast(1.0f + __expf(-v)); }
__device__ __forceinline__ float tanh_fast(float v) {
    return fmaf(-2.0f, rcp_fast(1.0f + __expf(2.0f * v)), 1.0f);
}

// One-block repack (unchanged layout): fold temporal_proj into layer-0 input
// projection; lay LSTM weights in exact consumption order (wave owns 2 units).
__global__ void repack(const float* __restrict__ Wtp,  const float* __restrict__ btp,
                       const float* __restrict__ Wih0, const float* __restrict__ Whh0,
                       const float* __restrict__ bih0, const float* __restrict__ bhh0,
                       const float* __restrict__ Wih1, const float* __restrict__ Whh1,
                       const float* __restrict__ bih1, const float* __restrict__ bhh1,
                       const float* __restrict__ Wfc1, const float* __restrict__ bfc1,
                       const float* __restrict__ Wfc2, const float* __restrict__ bfc2,
                       float* __restrict__ ws)
{
    const int tid = threadIdx.x;  // 256 threads
    if (tid < 128) {
        int k = tid >> 2, g = tid & 3;
        int r = g * 32 + k;                 // PyTorch gate-major row (i,f,g,o)
        float u = 0.f, v = 0.f;
        for (int d = 0; d < 16; ++d) {
            u = fmaf(Wih0[r * 16 + d], Wtp[d], u);
            v = fmaf(Wih0[r * 16 + d], btp[d], v);
        }
        ws[OFF_UV + k * 8 + g]     = u;
        ws[OFF_UV + k * 8 + 4 + g] = v + bih0[r] + bhh0[r];
        ws[OFF_B1 + tid]           = bih1[r] + bhh1[r];   // [k*4+g]
    }
    for (int idx = tid; idx < 4096; idx += 256) {
        int w = idx >> 8, rem = idx & 255;
        int j4 = rem >> 5, rem2 = rem & 31;
        int u = rem2 >> 4, g = (rem2 >> 2) & 3, jj = rem2 & 3;
        int K = w * 2 + u, r = g * 32 + K;
        ws[OFF_W0 + idx] = Whh0[r * 32 + j4 * 4 + jj];
    }
    for (int idx = tid; idx < 8192; idx += 256) {
        int w = idx >> 9, rem = idx & 511;
        int j4 = rem >> 5, rem2 = rem & 31;
        int u = rem2 >> 4, g = (rem2 >> 2) & 3, jj = rem2 & 3;
        int K = w * 2 + u, r = g * 32 + K;
        ws[OFF_W1 + idx] = (j4 < 8) ? Wih1[r * 32 + j4 * 4 + jj]
                                    : Whh1[r * 32 + (j4 - 8) * 4 + jj];
    }
    for (int idx = tid; idx < 512; idx += 256) {
        int m = idx >> 5, j = idx & 31;
        ws[OFF_FC1 + idx] = Wfc1[j * 16 + m];
    }
    if (tid < 16) { ws[OFF_BFC1 + tid] = bfc1[tid]; ws[OFF_FC2 + tid] = Wfc2[tid]; }
    if (tid == 0) ws[OFF_BFC2] = bfc2[0];
}

// 256 nodes/block, 16 waves; wave w owns units [2w,2w+2); lane l handles the
// 4 nodes l, l+64, l+128, l+192. Each LDS-broadcast weight float4 now feeds
// 16 FMAs (R8: 8) -> per-node broadcast traffic halves (R8 evidence: LDS pipe
// bound, broadcasts dominate). h lives in a COALESCED transposed layout
// sh[col4][node*4+jj]: lane reads its node's 16B contiguous -> 2 dwords/bank
// per 16-lane phase = conflict-free (R8's stride-144 rows hit only 8/32
// banks -> 2x read cost).
// sh0 single-buffered (bar1 after read-phase, bar2 after writes); sh1
// parity-buffered (no barrier needed). 2 barriers/step.
// LDS total 151 KB -> 1 block/CU, 16 waves, 4/SIMD -> 128-VGPR budget;
// live set ~100 regs -> no spills (watch: VGPR=64 + big WRITE = budget fail).
__global__ __launch_bounds__(1024)
void lstm_main(const float* __restrict__ x, const float* __restrict__ ws,
               float* __restrict__ out)
{
    __shared__ __align__(16) float sw[13232];       // 52.9 KB weights
    __shared__ __align__(16) float sh0[8 * 1024];   // 32 KB  [col4][node*4+jj]
    __shared__ __align__(16) float sh1[2 * 8 * 1024]; // 64 KB [parity][col4][node*4+jj]

    const int tid  = threadIdx.x;
    const int lane = tid & 63;
    const int wv   = __builtin_amdgcn_readfirstlane(tid >> 6);  // 0..15
    const int K0   = wv * 2;
    const int b0   = blockIdx.x * 256;

    // stage weights, zero h
    for (int i = tid; i < W_TOTAL; i += 1024) sw[i] = ws[i];
    for (int i = tid; i < 8 * 1024; i += 1024) { sh0[i] = 0.f; sh1[i] = 0.f; }

    int xi[4];
#pragma unroll
    for (int m = 0; m < 4; ++m) {
        int n = b0 + lane + 64 * m;
        xi[m] = (n < NN) ? n : 0;
    }

    float c0[2][4], c1[2][4];
#pragma unroll
    for (int u = 0; u < 2; ++u)
#pragma unroll
        for (int m = 0; m < 4; ++m) { c0[u][m] = 0.f; c1[u][m] = 0.f; }

    __syncthreads();

    const float* uvp = sw + OFF_UV + K0 * 8;
    const float* b1p = sw + OFF_B1 + K0 * 4;

    float xc[4], xn[4];
#pragma unroll
    for (int m = 0; m < 4; ++m) xc[m] = x[(size_t)xi[m] * 32 + 20];

#pragma unroll 1
    for (int t = 0; t < SEQ; ++t) {
        const int p = t & 1, np = p ^ 1;
#pragma unroll
        for (int m = 0; m < 4; ++m)
            xn[m] = (t + 1 < SEQ) ? x[(size_t)xi[m] * 32 + 21 + t] : 0.f;

        float a[2][4][4];   // [u][g][m]

        // ---------------- layer 0 (reads sh0 old) ----------------
#pragma unroll
        for (int u = 0; u < 2; ++u)
#pragma unroll
            for (int g = 0; g < 4; ++g) {
                const float uu = uvp[u * 8 + g], vv = uvp[u * 8 + 4 + g];
#pragma unroll
                for (int m = 0; m < 4; ++m) a[u][g][m] = fmaf(xc[m], uu, vv);
            }
#pragma unroll
        for (int j4 = 0; j4 < 8; ++j4) {
            float4 h[4];
#pragma unroll
            for (int m = 0; m < 4; ++m)
                h[m] = *(const float4*)&sh0[j4 * 1024 + (lane + 64 * m) * 4];
            const float* wp = sw + OFF_W0 + (wv * 8 + j4) * 32;
#pragma unroll
            for (int u = 0; u < 2; ++u)
#pragma unroll
                for (int g = 0; g < 4; ++g) {
                    const float4 q = *(const float4*)(wp + u * 16 + g * 4); // broadcast
#pragma unroll
                    for (int m = 0; m < 4; ++m) {
                        float av = a[u][g][m];
                        av = fmaf(q.x, h[m].x, av);
                        av = fmaf(q.y, h[m].y, av);
                        av = fmaf(q.z, h[m].z, av);
                        av = fmaf(q.w, h[m].w, av);
                        a[u][g][m] = av;
                    }
                }
        }
        float hn[2][4];
#pragma unroll
        for (int u = 0; u < 2; ++u)
#pragma unroll
            for (int m = 0; m < 4; ++m) {
                const float gi = sigm(a[u][0][m]), gf = sigm(a[u][1][m]);
                const float gg = tanh_fast(a[u][2][m]), go = sigm(a[u][3][m]);
                const float cc = fmaf(gf, c0[u][m], gi * gg);
                c0[u][m] = cc;
                hn[u][m] = go * tanh_fast(cc);
            }
        __syncthreads();   // bar1: all sh0 reads done
#pragma unroll
        for (int u = 0; u < 2; ++u) {
            const int K = K0 + u;
#pragma unroll
            for (int m = 0; m < 4; ++m)
                sh0[(K >> 2) * 1024 + (lane + 64 * m) * 4 + (K & 3)] = hn[u][m];
        }
        __syncthreads();   // bar2: sh0 new visible

        // ---------------- layer 1 (reads sh0 new + sh1[p], writes sh1[np]) ----
#pragma unroll
        for (int u = 0; u < 2; ++u)
#pragma unroll
            for (int g = 0; g < 4; ++g) {
                const float bb = b1p[u * 4 + g];
#pragma unroll
                for (int m = 0; m < 4; ++m) a[u][g][m] = bb;
            }
#pragma unroll
        for (int j4 = 0; j4 < 16; ++j4) {
            float4 h[4];
#pragma unroll
            for (int m = 0; m < 4; ++m) {
                const int i4 = (lane + 64 * m) * 4;
                h[m] = (j4 < 8)
                     ? *(const float4*)&sh0[j4 * 1024 + i4]
                     : *(const float4*)&sh1[p * 8192 + (j4 - 8) * 1024 + i4];
            }
            const float* wp = sw + OFF_W1 + (wv * 16 + j4) * 32;
#pragma unroll
            for (int u = 0; u < 2; ++u)
#pragma unroll
                for (int g = 0; g < 4; ++g) {
                    const float4 q = *(const float4*)(wp + u * 16 + g * 4); // broadcast
#pragma unroll
                    for (int m = 0; m < 4; ++m) {
                        float av = a[u][g][m];
                        av = fmaf(q.x, h[m].x, av);
                        av = fmaf(q.y, h[m].y, av);
                        av = fmaf(q.z, h[m].z, av);
                        av = fmaf(q.w, h[m].w, av);
                        a[u][g][m] = av;
                    }
                }
        }
#pragma unroll
        for (int u = 0; u < 2; ++u) {
            const int K = K0 + u;
#pragma unroll
            for (int m = 0; m < 4; ++m) {
                const float gi = sigm(a[u][0][m]), gf = sigm(a[u][1][m]);
                const float gg = tanh_fast(a[u][2][m]), go = sigm(a[u][3][m]);
                const float cc = fmaf(gf, c1[u][m], gi * gg);
                c1[u][m] = cc;
                sh1[np * 8192 + (K >> 2) * 1024 + (lane + 64 * m) * 4 + (K & 3)]
                    = go * tanh_fast(cc);
            }
        }
        // no barrier: sh1 parity-buffered; next step's bar1/bar2 order everything
#pragma unroll
        for (int m = 0; m < 4; ++m) xc[m] = xn[m];
    }

    __syncthreads();   // final h1 (parity 0 after t=11) visible

    // -------- fc head: waves 0-3, wave w handles node group m=w ----------
    if (wv < 4) {
        const int node = b0 + lane + 64 * wv;
        const int i4   = (lane + 64 * wv) * 4;
        float4 hf[8];
#pragma unroll
        for (int j4 = 0; j4 < 8; ++j4)
            hf[j4] = *(const float4*)&sh1[j4 * 1024 + i4];   // parity 0
        float acc2 = sw[OFF_BFC2];
#pragma unroll
        for (int mm = 0; mm < 16; ++mm) {
            const float* fp = sw + OFF_FC1 + mm * 32;
            float y = sw[OFF_BFC1 + mm];
#pragma unroll
            for (int j4 = 0; j4 < 8; ++j4) {
                y = fmaf(fp[j4 * 4 + 0], hf[j4].x, y);
                y = fmaf(fp[j4 * 4 + 1], hf[j4].y, y);
                y = fmaf(fp[j4 * 4 + 2], hf[j4].z, y);
                y = fmaf(fp[j4 * 4 + 3], hf[j4].w, y);
            }
            acc2 = fmaf(fmaxf(y, 0.f), sw[OFF_FC2 + mm], acc2);
        }
        if (node < NN) out[node] = acc2;
    }
}

extern "C" void kernel_launch(void* const* d_in, const int* in_sizes, int n_in,
                              void* d_out, int out_size, void* d_ws, size_t ws_size,
                              hipStream_t stream) {
    (void)in_sizes; (void)n_in; (void)out_size; (void)ws_size;
    const float* x    = (const float*)d_in[0];
    // d_in[1] edge_index and d_in[2..9] (GCN weights) are dead code in the reference
    const float* Wtp  = (const float*)d_in[10];
    const float* btp  = (const float*)d_in[11];
    const float* Wih0 = (const float*)d_in[12];
    const float* Whh0 = (const float*)d_in[13];
    const float* bih0 = (const float*)d_in[14];
    const float* bhh0 = (const float*)d_in[15];
    const float* Wih1 = (const float*)d_in[16];
    const float* Whh1 = (const float*)d_in[17];
    const float* bih1 = (const float*)d_in[18];
    const float* bhh1 = (const float*)d_in[19];
    const float* Wfc1 = (const float*)d_in[20];
    const float* bfc1 = (const float*)d_in[21];
    const float* Wfc2 = (const float*)d_in[22];
    const float* bfc2 = (const float*)d_in[23];
    float* ws  = (float*)d_ws;
    float* out = (float*)d_out;

    hipLaunchKernelGGL(repack, dim3(1), dim3(256), 0, stream,
                       Wtp, btp, Wih0, Whh0, bih0, bhh0,
                       Wih1, Whh1, bih1, bhh1, Wfc1, bfc1, Wfc2, bfc2, ws);
    hipLaunchKernelGGL(lstm_main, dim3((NN + 255) / 256), dim3(1024), 0, stream,
                       x, ws, out);
}